// Round 2
// baseline (699.146 us; speedup 1.0000x reference)
//
#include <hip/hip_runtime.h>
#include <cstdint>
#include <cstddef>

#define BB 128
#define TT 512
#define DD 100
#define HH 100
#define NG 400   // 4*H
#define LL 25
#define F_LOG2E 1.44269504088896340736f
#define F_LN2   0.69314718055994530942f

typedef __decltype(__builtin_amdgcn_cvt_pkrtz(0.f, 0.f)) h2_t;

__device__ __forceinline__ h2_t bc_h2(unsigned int u) {
  return __builtin_bit_cast(h2_t, u);
}

__device__ __forceinline__ float fdot2(h2_t a, h2_t b, float c) {
#if defined(__has_builtin)
#if __has_builtin(__builtin_amdgcn_fdot2)
  return __builtin_amdgcn_fdot2(a, b, c, false);
#else
  return c + (float)a[0] * (float)b[0] + (float)a[1] * (float)b[1];
#endif
#else
  return c + (float)a[0] * (float)b[0] + (float)a[1] * (float)b[1];
#endif
}

__device__ __forceinline__ float fexp2(float x) { return __builtin_amdgcn_exp2f(x); }
__device__ __forceinline__ float flog2(float x) { return __builtin_amdgcn_logf(x); }
__device__ __forceinline__ float frcp(float x)  { return __builtin_amdgcn_rcpf(x); }

__device__ __forceinline__ float sigmoid_f(float x) {
  return frcp(1.f + fexp2(-F_LOG2E * x));
}
__device__ __forceinline__ float tanh_f(float x) {
  float e = fexp2(2.f * F_LOG2E * x);
  return 1.f - 2.f * frcp(e + 1.f);
}

__device__ __forceinline__ float rl(float v, int l) {
  return __builtin_bit_cast(float, __builtin_amdgcn_readlane(__builtin_bit_cast(int, v), l));
}

// ---------------------------------------------------------------------------
// gin GEMM: gin[(b*2+dir)*512+t][perm-pos p] = b_ih[r]+b_hh[r] + x[b,t]·W_ih[r,:]
// where the gate at output position p is r = (p&3)*100 + (p>>2), so the scan's
// thread tid directly reads position tid. f16 output.
// Block: 256 threads, 128 rows, one direction. W rows in registers (f16x2),
// X tile staged in LDS (uniform broadcast reads -> no conflicts).
// ---------------------------------------------------------------------------
__global__ __launch_bounds__(256, 2) void gin_gemm(
    const int* __restrict__ tok, const float* __restrict__ emb,
    const float* __restrict__ w_ih_f, const float* __restrict__ b_ih_f,
    const float* __restrict__ b_hh_f,
    const float* __restrict__ w_ih_b, const float* __restrict__ b_ih_b,
    const float* __restrict__ b_hh_b,
    unsigned short* __restrict__ gin16)
{
  const int tid  = threadIdx.x;
  const int tile = blockIdx.x & 511;
  const int dir  = blockIdx.x >> 9;
  const size_t m0 = (size_t)tile * 128;
  const int b  = (int)(m0 >> 9);
  const int t0 = (int)(m0 & 511);

  const float* w_ih = dir ? w_ih_b : w_ih_f;
  const float* b_ih = dir ? b_ih_b : b_ih_f;
  const float* b_hh = dir ? b_hh_b : b_hh_f;

  __shared__ __align__(16) unsigned int xs[128 * 52];  // 52-dword stride: 16B aligned rows

  for (int i = tid; i < 128 * 25; i += 256) {
    int r = i / 25;
    int q = i - r * 25;
    int tk = tok[m0 + r];
    float4 v = ((const float4*)(emb + (size_t)tk * DD))[q];
    xs[r * 52 + 2 * q]     = __builtin_bit_cast(unsigned int, __builtin_amdgcn_cvt_pkrtz(v.x, v.y));
    xs[r * 52 + 2 * q + 1] = __builtin_bit_cast(unsigned int, __builtin_amdgcn_cvt_pkrtz(v.z, v.w));
  }

  const int p0 = tid;
  const int p1 = tid + 256;
  const bool has2 = (p1 < NG);
  const int r0 = (p0 & 3) * 100 + (p0 >> 2);
  const int r1 = (p1 & 3) * 100 + (p1 >> 2);

  h2_t w0[50], w1[50];
  float bias0 = b_ih[r0] + b_hh[r0];
  float bias1 = has2 ? (b_ih[r1] + b_hh[r1]) : 0.f;
  {
    const float4* wr = (const float4*)(w_ih + (size_t)r0 * DD);
#pragma unroll
    for (int kk = 0; kk < 25; ++kk) {
      float4 a = wr[kk];
      w0[2 * kk]     = __builtin_amdgcn_cvt_pkrtz(a.x, a.y);
      w0[2 * kk + 1] = __builtin_amdgcn_cvt_pkrtz(a.z, a.w);
    }
  }
  if (has2) {
    const float4* wr = (const float4*)(w_ih + (size_t)r1 * DD);
#pragma unroll
    for (int kk = 0; kk < 25; ++kk) {
      float4 a = wr[kk];
      w1[2 * kk]     = __builtin_amdgcn_cvt_pkrtz(a.x, a.y);
      w1[2 * kk + 1] = __builtin_amdgcn_cvt_pkrtz(a.z, a.w);
    }
  }
  __syncthreads();

  const size_t idx_base = (size_t)b * 1024 + (size_t)dir * 512 + t0;
  for (int r = 0; r < 128; ++r) {
    const unsigned int* xr = xs + r * 52;
    float a0 = bias0, a1 = 0.f, c0 = bias1, c1 = 0.f;
#pragma unroll
    for (int g = 0; g < 12; ++g) {
      uint4 u = ((const uint4*)xr)[g];
      a0 = fdot2(w0[4 * g],     bc_h2(u.x), a0);
      a1 = fdot2(w0[4 * g + 1], bc_h2(u.y), a1);
      a0 = fdot2(w0[4 * g + 2], bc_h2(u.z), a0);
      a1 = fdot2(w0[4 * g + 3], bc_h2(u.w), a1);
      if (has2) {
        c0 = fdot2(w1[4 * g],     bc_h2(u.x), c0);
        c1 = fdot2(w1[4 * g + 1], bc_h2(u.y), c1);
        c0 = fdot2(w1[4 * g + 2], bc_h2(u.z), c0);
        c1 = fdot2(w1[4 * g + 3], bc_h2(u.w), c1);
      }
    }
    {
      unsigned int ux = xr[48], uy = xr[49];
      a0 = fdot2(w0[48], bc_h2(ux), a0);
      a1 = fdot2(w0[49], bc_h2(uy), a1);
      if (has2) {
        c0 = fdot2(w1[48], bc_h2(ux), c0);
        c1 = fdot2(w1[49], bc_h2(uy), c1);
      }
    }
    size_t orow = (idx_base + (size_t)r) * NG;
    gin16[orow + p0] = __builtin_bit_cast(unsigned short, (__fp16)(a0 + a1));
    if (has2)
      gin16[orow + p1] = __builtin_bit_cast(unsigned short, (__fp16)(c0 + c1));
  }
}

// ---------------------------------------------------------------------------
// LSTM scan v2: one block per (batch, direction), 448 threads (400 active).
// Thread tid: unit j = tid>>2, gate type gt = tid&3 (i,f,g,o). Per step:
//   acc = gin (prefetched 2 deep from global, f16) + h·W_hh (50 fdot2,
//   4 independent accumulators), unified sigmoid/tanh via exp2+rcp, gate
//   exchange via in-wave shfl, cell update computed redundantly in all 4
//   lanes of a unit, h written f16 to double-buffered LDS + f32 to global.
// ONE barrier per step.
// ---------------------------------------------------------------------------
__global__ __launch_bounds__(448) void lstm_scan2(
    const unsigned short* __restrict__ gin16,
    const float* __restrict__ w_hh_f, const float* __restrict__ w_hh_b,
    float* __restrict__ hc)
{
  const int tid = threadIdx.x;
  const int b   = blockIdx.x & 127;
  const int dir = blockIdx.x >> 7;
  const float* w_hh = dir ? w_hh_b : w_hh_f;

  __shared__ __align__(16) unsigned int hls[2][52];

  const int j  = tid >> 2;
  const int gt = tid & 3;
  const bool act = tid < NG;
  const int lane = tid & 63;
  const int bl = lane & ~3;

  h2_t whh[50];
  if (act) {
    const float4* wr = (const float4*)(w_hh + (size_t)(gt * 100 + j) * HH);
#pragma unroll
    for (int kk = 0; kk < 25; ++kk) {
      float4 a = wr[kk];
      whh[2 * kk]     = __builtin_amdgcn_cvt_pkrtz(a.x, a.y);
      whh[2 * kk + 1] = __builtin_amdgcn_cvt_pkrtz(a.z, a.w);
    }
  }
  if (tid < 52) { hls[0][tid] = 0u; hls[1][tid] = 0u; }

  const unsigned short* gb = gin16 + ((size_t)(b * 2 + dir) * TT) * NG + tid;
  float* hcb = hc + (size_t)b * TT * 200 + dir * 100 + j;

  float c = 0.f;
  unsigned short g0 = 0, g1 = 0;
  if (act) {
    int tA = dir ? 511 : 0;
    int tB = dir ? 510 : 1;
    g0 = gb[(size_t)tA * NG];
    g1 = gb[(size_t)tB * NG];
  }
  __syncthreads();

  for (int t = 0; t < TT; ++t) {
    if (act) {
      // depth-2 prefetch of gin for step t+2
      int tn = (t + 2 < TT) ? t + 2 : TT - 1;
      int ttn = dir ? (TT - 1 - tn) : tn;
      unsigned short g2 = gb[(size_t)ttn * NG];

      float gval = (float)__builtin_bit_cast(__fp16, g0);
      const unsigned int* hp = hls[t & 1];
      float a0 = gval, a1 = 0.f, a2 = 0.f, a3 = 0.f;
#pragma unroll
      for (int g = 0; g < 12; ++g) {
        uint4 u = ((const uint4*)hp)[g];
        a0 = fdot2(whh[4 * g],     bc_h2(u.x), a0);
        a1 = fdot2(whh[4 * g + 1], bc_h2(u.y), a1);
        a2 = fdot2(whh[4 * g + 2], bc_h2(u.z), a2);
        a3 = fdot2(whh[4 * g + 3], bc_h2(u.w), a3);
      }
      {
        unsigned int ux = hp[48], uy = hp[49];
        a0 = fdot2(whh[48], bc_h2(ux), a0);
        a1 = fdot2(whh[49], bc_h2(uy), a1);
      }
      float gate = (a0 + a1) + (a2 + a3);
      // unified activation: sigmoid for i,f,o; tanh for g (gt==2)
      float kk = (gt == 2) ? (2.f * F_LOG2E) : (-F_LOG2E);
      float y  = fexp2(kk * gate);
      float rr = frcp(1.f + y);
      float actv = (gt == 2) ? fmaf(-2.f, rr, 1.f) : rr;

      float iv = __shfl(actv, bl);
      float fv = __shfl(actv, bl + 1);
      float gv = __shfl(actv, bl + 2);
      float ov = __shfl(actv, bl + 3);
      c = fmaf(fv, c, iv * gv);
      float hv = ov * tanh_f(c);

      int tt = dir ? (TT - 1 - t) : t;
      if (gt == 0) {
        ((__fp16*)(hls[(t + 1) & 1]))[j] = (__fp16)hv;
        hcb[(size_t)tt * 200] = hv;
      }
      g0 = g1; g1 = g2;
    }
    __syncthreads();
  }
}

// ---------------------------------------------------------------------------
// FALLBACK LSTM scan (x-side computed in-scan) for small ws_size.
// ---------------------------------------------------------------------------
__global__ __launch_bounds__(512, 2) void lstm_scan_fb(
    const int* __restrict__ tok, const float* __restrict__ emb,
    const float* __restrict__ w_ih_f, const float* __restrict__ w_hh_f,
    const float* __restrict__ b_ih_f, const float* __restrict__ b_hh_f,
    const float* __restrict__ w_ih_b, const float* __restrict__ w_hh_b,
    const float* __restrict__ b_ih_b, const float* __restrict__ b_hh_b,
    float* __restrict__ hc)
{
  const int tid = threadIdx.x;
  const int b   = blockIdx.x & 127;
  const int dir = blockIdx.x >> 7;

  const float* w_ih = dir ? w_ih_b : w_ih_f;
  const float* w_hh = dir ? w_hh_b : w_hh_f;
  const float* b_ih = dir ? b_ih_b : b_ih_f;
  const float* b_hh = dir ? b_hh_b : b_hh_f;

  __shared__ __align__(16) unsigned int xs[2][64];
  __shared__ __align__(16) unsigned int hls[64];
  __shared__ float gl[NG];

  h2_t wih[50], whh[50];
  float bias = 0.f;
  if (tid < NG) {
    const float4* wi = (const float4*)(w_ih + tid * DD);
    const float4* wh = (const float4*)(w_hh + tid * DD);
#pragma unroll
    for (int kk = 0; kk < 25; ++kk) {
      float4 a = wi[kk];
      wih[2 * kk]     = __builtin_amdgcn_cvt_pkrtz(a.x, a.y);
      wih[2 * kk + 1] = __builtin_amdgcn_cvt_pkrtz(a.z, a.w);
      float4 c = wh[kk];
      whh[2 * kk]     = __builtin_amdgcn_cvt_pkrtz(c.x, c.y);
      whh[2 * kk + 1] = __builtin_amdgcn_cvt_pkrtz(c.z, c.w);
    }
    bias = b_ih[tid] + b_hh[tid];
  }
  if (tid < 2) { xs[0][50 + tid] = 0u; xs[1][50 + tid] = 0u; hls[50 + tid] = 0u; }
  if (tid < 50) hls[tid] = 0u;

  const int base = b * TT;
  if (tid >= 448 && tid < 498) {
    int tt0 = dir ? (TT - 1) : 0;
    int i = tid - 448;
    int tk = tok[base + tt0];
    float2 v = ((const float2*)(emb + (size_t)tk * DD))[i];
    xs[0][i] = __builtin_bit_cast(unsigned int, __builtin_amdgcn_cvt_pkrtz(v.x, v.y));
  }
  __syncthreads();

  float cst = 0.f;
  float* hcb = hc + (size_t)base * 200 + dir * 100;

  for (int t = 0; t < TT; ++t) {
    const int buf = t & 1;
    const int tt  = dir ? (TT - 1 - t) : t;

    if (tid < NG) {
      float acc = bias, accb = 0.f, accc = 0.f, accd = 0.f;
      const unsigned int* xp = xs[buf];
#pragma unroll
      for (int g = 0; g < 13; ++g) {
        uint4 u = ((const uint4*)xp)[g];
        const int k = 4 * g;
        acc  = fdot2(wih[k],     bc_h2(u.x), acc);
        accb = fdot2(wih[k + 1], bc_h2(u.y), accb);
        if (k + 2 < 50) accc = fdot2(wih[k + 2], bc_h2(u.z), accc);
        if (k + 3 < 50) accd = fdot2(wih[k + 3], bc_h2(u.w), accd);
      }
#pragma unroll
      for (int g = 0; g < 13; ++g) {
        uint4 u = ((const uint4*)hls)[g];
        const int k = 4 * g;
        acc  = fdot2(whh[k],     bc_h2(u.x), acc);
        accb = fdot2(whh[k + 1], bc_h2(u.y), accb);
        if (k + 2 < 50) accc = fdot2(whh[k + 2], bc_h2(u.z), accc);
        if (k + 3 < 50) accd = fdot2(whh[k + 3], bc_h2(u.w), accd);
      }
      float accs = (acc + accb) + (accc + accd);
      float av = (tid >= 200 && tid < 300) ? tanh_f(accs) : sigmoid_f(accs);
      gl[tid] = av;
    } else if (tid >= 448 && tid < 498 && t < TT - 1) {
      int ttn = dir ? (TT - 2 - t) : (t + 1);
      int i = tid - 448;
      int tk = tok[base + ttn];
      float2 v = ((const float2*)(emb + (size_t)tk * DD))[i];
      xs[buf ^ 1][i] = __builtin_bit_cast(unsigned int, __builtin_amdgcn_cvt_pkrtz(v.x, v.y));
    }
    __syncthreads();

    if (tid < HH) {
      float gi = gl[tid], gf = gl[tid + 100], gg = gl[tid + 200], go = gl[tid + 300];
      cst = gf * cst + gi * gg;
      float hv = go * tanh_f(cst);
      ((__fp16*)hls)[tid] = (__fp16)hv;
      hcb[(size_t)tt * 200 + tid] = hv;
    }
    __syncthreads();
  }
}

// ---------------------------------------------------------------------------
// Emissions: em[m, l] = b_tag[l] + sum_k hc[m,k] * w_tag[l,k]
// ---------------------------------------------------------------------------
__global__ __launch_bounds__(256, 2) void emis_kernel(
    const float* __restrict__ hc, const float* __restrict__ w_tag,
    const float* __restrict__ b_tag, float* __restrict__ em)
{
  __shared__ float hsh[64 * 201];
  const int tid = threadIdx.x;
  const size_t m0 = (size_t)blockIdx.x * 64;

  for (int i = tid; i < 64 * 200; i += 256) {
    int r = i / 200;
    int k = i - r * 200;
    hsh[r * 201 + k] = hc[m0 * 200 + i];
  }
  __syncthreads();

  const int r = tid & 63, q = tid >> 6;
  int lidx[7];
  bool lv[7];
  float acc[7];
#pragma unroll
  for (int ii = 0; ii < 7; ++ii) {
    int l = q + 4 * ii;
    lv[ii] = (l < LL);
    lidx[ii] = lv[ii] ? l : 0;
    acc[ii] = lv[ii] ? b_tag[lidx[ii]] : 0.f;
  }
  const float* hrow = hsh + r * 201;
#pragma unroll 4
  for (int k = 0; k < 200; ++k) {
    float hv = hrow[k];
#pragma unroll
    for (int ii = 0; ii < 7; ++ii)
      acc[ii] += hv * w_tag[lidx[ii] * 200 + k];
  }
#pragma unroll
  for (int ii = 0; ii < 7; ++ii)
    if (lv[ii]) em[(m0 + r) * LL + lidx[ii]] = acc[ii];
}

// ---------------------------------------------------------------------------
// CRF gold path score
// ---------------------------------------------------------------------------
__global__ __launch_bounds__(512, 2) void crf_gold(
    const int* __restrict__ tags, const int* __restrict__ lengths,
    const float* __restrict__ em, const float* __restrict__ trans,
    const float* __restrict__ startt, const float* __restrict__ endt,
    float* __restrict__ gold)
{
  const int b = blockIdx.x, t = threadIdx.x;
  const int len = lengths[b];
  float term = 0.f;
  if (t < len) {
    int tg = tags[b * TT + t];
    float e = em[((size_t)b * TT + t) * LL + tg];
    if (t == 0) term = startt[tg] + e;
    else        term = trans[tags[b * TT + t - 1] * LL + tg] + e;
    if (t == len - 1) term += endt[tg];
  }
  __shared__ float red[8];
  for (int o = 32; o > 0; o >>= 1) term += __shfl_down(term, o);
  if ((t & 63) == 0) red[t >> 6] = term;
  __syncthreads();
  if (t == 0) {
    float s = 0.f;
#pragma unroll
    for (int w = 0; w < 8; ++w) s += red[w];
    gold[b] = s;
  }
}

// ---------------------------------------------------------------------------
// CRF partition, v2: split fwd/bwd scan; inner lse split across half-waves
// (lanes 0..24 handle source i=0..12, lanes 32..56 handle i=13..24, combine
// via shfl_xor(32)); em software-pipelined one step ahead. alpha mirrored
// in both halves. log2 domain with lane-0 shift for range safety.
// ---------------------------------------------------------------------------
__global__ __launch_bounds__(64) void crf_scan2(
    const float* __restrict__ em, const float* __restrict__ trans,
    const float* __restrict__ startt, const float* __restrict__ endt,
    float* __restrict__ ab)
{
  const int lane = threadIdx.x;
  const int b    = blockIdx.x >> 1;
  const int side = blockIdx.x & 1;
  const int half = lane >> 5;
  const int jl   = lane & 31;
  const int j    = (jl < LL) ? jl : 0;
  const float* emb_ = em + (size_t)b * TT * LL;
  const int ibase = half ? 13 : 0;
  const int icnt  = half ? 12 : 13;

  float tc[13];
#pragma unroll
  for (int k = 0; k < 13; ++k) {
    int i = ibase + k;
    float tv = 0.f;
    if (k < icnt) tv = (side == 0) ? trans[i * LL + j] : trans[j * LL + i];
    tc[k] = (k < icnt) ? tv * F_LOG2E : -100000.f;
  }

  float a, C = 0.f;
  if (side == 0) {
    a = (startt[j] + emb_[j]) * F_LOG2E;
    float emn = emb_[LL + j];
    for (int t = 1; t < 256; ++t) {
      float emc = emn;
      int tn = (t + 1 < 256) ? t + 1 : t;
      emn = emb_[(size_t)tn * LL + j];
      float s = rl(a, 0); a -= s; C += s;
      float p0 = 0.f, p1 = 0.f;
#pragma unroll
      for (int k = 0; k < 13; ++k) {
        float ai = __shfl(a, ibase + k);
        float e = fexp2(ai + tc[k]);
        if (k & 1) p1 += e; else p0 += e;
      }
      float p = p0 + p1;
      p += __shfl_xor(p, 32);
      a = flog2(p) + emc * F_LOG2E;
    }
  } else {
    a = endt[j] * F_LOG2E;
    float emn = emb_[(size_t)(TT - 1) * LL + j];
    for (int stp = 0; stp < 256; ++stp) {
      int t1 = TT - 1 - stp;
      float emc = emn;
      int t1n = (stp + 1 < 256) ? (t1 - 1) : t1;
      emn = emb_[(size_t)t1n * LL + j];
      float v = a + emc * F_LOG2E;
      float s = rl(v, 0); v -= s; C += s;
      float p0 = 0.f, p1 = 0.f;
#pragma unroll
      for (int k = 0; k < 13; ++k) {
        float vi = __shfl(v, ibase + k);
        float e = fexp2(vi + tc[k]);
        if (k & 1) p1 += e; else p0 += e;
      }
      float p = p0 + p1;
      p += __shfl_xor(p, 32);
      a = flog2(p);
    }
  }
  if (lane < LL)
    ab[((size_t)b * 2 + side) * LL + lane] = (a + C) * F_LN2;
}

// ---------------------------------------------------------------------------
// Final reduce
// ---------------------------------------------------------------------------
__global__ __launch_bounds__(128, 4) void crf_final(
    const float* __restrict__ ab, const float* __restrict__ gold,
    float* __restrict__ out)
{
  const int b = threadIdx.x;
  float v[LL];
  float m = -1e30f;
#pragma unroll
  for (int l = 0; l < LL; ++l) {
    v[l] = ab[((size_t)b * 2) * LL + l] + ab[((size_t)b * 2 + 1) * LL + l];
    m = fmaxf(m, v[l]);
  }
  float s = 0.f;
#pragma unroll
  for (int l = 0; l < LL; ++l) s += fexp2((v[l] - m) * F_LOG2E);
  float nll = (m + flog2(s) * F_LN2) - gold[b];

  for (int o = 32; o > 0; o >>= 1) nll += __shfl_down(nll, o);
  __shared__ float r2[2];
  if ((b & 63) == 0) r2[b >> 6] = nll;
  __syncthreads();
  if (b == 0) out[0] = r2[0] + r2[1];
}

extern "C" void kernel_launch(void* const* d_in, const int* in_sizes, int n_in,
                              void* d_out, int out_size, void* d_ws, size_t ws_size,
                              hipStream_t stream) {
  const int*   tok   = (const int*)d_in[0];
  const int*   tags  = (const int*)d_in[1];
  const int*   lens  = (const int*)d_in[2];
  const float* emb   = (const float*)d_in[3];
  const float* wif   = (const float*)d_in[4];
  const float* whf   = (const float*)d_in[5];
  const float* bif   = (const float*)d_in[6];
  const float* bhf   = (const float*)d_in[7];
  const float* wib   = (const float*)d_in[8];
  const float* whb   = (const float*)d_in[9];
  const float* bib   = (const float*)d_in[10];
  const float* bhb   = (const float*)d_in[11];
  const float* wtag  = (const float*)d_in[12];
  const float* btag  = (const float*)d_in[13];
  const float* trans = (const float*)d_in[14];
  const float* st    = (const float*)d_in[15];
  const float* en    = (const float*)d_in[16];

  float* ws   = (float*)d_ws;
  float* hc   = ws;                          // 13,107,200 f32
  float* em   = ws + 13107200;               //  1,638,400 f32
  float* gold = ws + 13107200 + 1638400;     // 128
  float* ab   = gold + 128;                  // 6400
  unsigned short* gin16 = (unsigned short*)(ab + 6400);  // 52,428,800 ushort

  const size_t need = 163866112ULL;  // 59,008,512 + 104,857,600 bytes

  if (ws_size >= need) {
    gin_gemm<<<1024, 256, 0, stream>>>(tok, emb, wif, bif, bhf, wib, bib, bhb, gin16);
    lstm_scan2<<<256, 448, 0, stream>>>(gin16, whf, whb, hc);
  } else {
    lstm_scan_fb<<<256, 512, 0, stream>>>(tok, emb, wif, whf, bif, bhf,
                                          wib, whb, bib, bhb, hc);
  }
  emis_kernel<<<1024, 256, 0, stream>>>(hc, wtag, btag, em);
  crf_gold<<<128, 512, 0, stream>>>(tags, lens, em, trans, st, en, gold);
  crf_scan2<<<256, 64, 0, stream>>>(em, trans, st, en, ab);
  crf_final<<<1, 128, 0, stream>>>(ab, gold, (float*)d_out);
}

// Round 3
// 625.705 us; speedup vs baseline: 1.1174x; 1.1174x over previous
//
#include <hip/hip_runtime.h>
#include <cstdint>
#include <cstddef>

#define BB 128
#define TT 512
#define DD 100
#define HH 100
#define NG 400   // 4*H
#define LL 25
#define F_LOG2E 1.44269504088896340736f
#define F_LN2   0.69314718055994530942f

typedef __decltype(__builtin_amdgcn_cvt_pkrtz(0.f, 0.f)) h2_t;

__device__ __forceinline__ h2_t bc_h2(unsigned int u) {
  return __builtin_bit_cast(h2_t, u);
}
__device__ __forceinline__ unsigned int pk(float x, float y) {
  return __builtin_bit_cast(unsigned int, __builtin_amdgcn_cvt_pkrtz(x, y));
}

__device__ __forceinline__ float fdot2(h2_t a, h2_t b, float c) {
#if __has_builtin(__builtin_amdgcn_fdot2)
  return __builtin_amdgcn_fdot2(a, b, c, false);
#else
  return c + (float)a[0] * (float)b[0] + (float)a[1] * (float)b[1];
#endif
}

__device__ __forceinline__ float fexp2(float x) { return __builtin_amdgcn_exp2f(x); }
__device__ __forceinline__ float flog2(float x) { return __builtin_amdgcn_logf(x); }
__device__ __forceinline__ float frcp(float x)  { return __builtin_amdgcn_rcpf(x); }

__device__ __forceinline__ float sigmoid_f(float x) {
  return frcp(1.f + fexp2(-F_LOG2E * x));
}
__device__ __forceinline__ float tanh_f(float x) {
  float e = fexp2(2.f * F_LOG2E * x);
  return 1.f - 2.f * frcp(e + 1.f);
}

__device__ __forceinline__ float rl(float v, int l) {
  return __builtin_bit_cast(float, __builtin_amdgcn_readlane(__builtin_bit_cast(int, v), l));
}

// LDS-visibility-only barrier: waits lgkmcnt(0) but leaves vmcnt unconstrained,
// so global prefetch loads / stores stay in flight across the barrier.
// imm 0xC07F: vmcnt=63 (bits [3:0]+[15:14]), expcnt=7, lgkmcnt=0.
__device__ __forceinline__ void lds_barrier() {
  __builtin_amdgcn_s_waitcnt(0xC07F);
  __builtin_amdgcn_s_barrier();
}

// ---------------------------------------------------------------------------
// gin GEMM v2: gin[(b*2+dir)*512+t][p] = bias[r] + x[b,t]·W_ih[r,:], where
// r = (p&3)*100 + (p>>2) (gate-interleaved so scan thread tid reads pos tid).
// 448 threads (400 active, ONE output column each -> 50-reg weight array in
// true VGPRs under __launch_bounds__(448,2)), 128 time-rows per block.
// ---------------------------------------------------------------------------
__global__ __launch_bounds__(448, 2) void gin_gemm2(
    const int* __restrict__ tok, const float* __restrict__ emb,
    const float* __restrict__ w_ih_f, const float* __restrict__ b_ih_f,
    const float* __restrict__ b_hh_f,
    const float* __restrict__ w_ih_b, const float* __restrict__ b_ih_b,
    const float* __restrict__ b_hh_b,
    unsigned short* __restrict__ gin16)
{
  const int tid  = threadIdx.x;
  const int tile = blockIdx.x & 511;
  const int dir  = blockIdx.x >> 9;
  const size_t m0 = (size_t)tile * 128;       // rows m0..m0+127, all same b
  const int b  = (int)(m0 >> 9);
  const int t0 = (int)(m0 & 511);

  const float* w_ih = dir ? w_ih_b : w_ih_f;
  const float* b_ih = dir ? b_ih_b : b_ih_f;
  const float* b_hh = dir ? b_hh_b : b_hh_f;

  __shared__ __align__(16) unsigned int xs[128 * 52];

  for (int i = tid; i < 128 * 25; i += 448) {
    int r = i / 25;
    int q = i - r * 25;
    int tk = tok[m0 + r];
    float4 v = ((const float4*)(emb + (size_t)tk * DD))[q];
    xs[r * 52 + 2 * q]     = pk(v.x, v.y);
    xs[r * 52 + 2 * q + 1] = pk(v.z, v.w);
  }

  const bool act = tid < NG;
  const int r0 = (tid & 3) * 100 + (tid >> 2);
  h2_t w0[50];
  float bias = 0.f;
  if (act) {
    const float4* wr = (const float4*)(w_ih + (size_t)r0 * DD);
#pragma unroll
    for (int kk = 0; kk < 25; ++kk) {
      float4 a = wr[kk];
      w0[2 * kk]     = __builtin_amdgcn_cvt_pkrtz(a.x, a.y);
      w0[2 * kk + 1] = __builtin_amdgcn_cvt_pkrtz(a.z, a.w);
    }
    bias = b_ih[r0] + b_hh[r0];
  }
  __syncthreads();

  if (act) {
    unsigned short* op = gin16 + ((size_t)(b * 2 + dir) * TT + t0) * NG + tid;
    for (int r = 0; r < 128; ++r) {
      const unsigned int* xr = xs + r * 52;
      float a0 = bias, a1 = 0.f, a2 = 0.f, a3 = 0.f;
#pragma unroll
      for (int g = 0; g < 12; ++g) {
        uint4 u = ((const uint4*)xr)[g];
        a0 = fdot2(w0[4 * g],     bc_h2(u.x), a0);
        a1 = fdot2(w0[4 * g + 1], bc_h2(u.y), a1);
        a2 = fdot2(w0[4 * g + 2], bc_h2(u.z), a2);
        a3 = fdot2(w0[4 * g + 3], bc_h2(u.w), a3);
      }
      a0 = fdot2(w0[48], bc_h2(xr[48]), a0);
      a1 = fdot2(w0[49], bc_h2(xr[49]), a1);
      *op = __builtin_bit_cast(unsigned short, (__fp16)((a0 + a1) + (a2 + a3)));
      op += NG;
    }
  }
}

// ---------------------------------------------------------------------------
// LSTM scan v3: one block per (batch, direction), 448 threads (400 active).
// Thread tid: unit j=tid>>2, gate gt=tid&3. W_hh row in VGPRs (LB(448,2)
// keeps the 50-reg array out of AGPRs). gin prefetched 2 steps deep; the
// in-loop barrier drains ONLY lgkmcnt so prefetch latency is hidden across
// 2 steps. h exchanged f16 via double-buffered LDS; hc written f16.
// ---------------------------------------------------------------------------
__global__ __launch_bounds__(448, 2) void lstm_scan3(
    const unsigned short* __restrict__ gin16,
    const float* __restrict__ w_hh_f, const float* __restrict__ w_hh_b,
    unsigned short* __restrict__ hc16)
{
  const int tid = threadIdx.x;
  const int b   = blockIdx.x & 127;
  const int dir = blockIdx.x >> 7;
  const float* w_hh = dir ? w_hh_b : w_hh_f;

  __shared__ __align__(16) unsigned int hls[2][52];

  const int j   = tid >> 2;
  const int gt  = tid & 3;
  const bool act = tid < NG;
  const int bl4 = (tid & 63) & ~3;

  h2_t whh[50];
  if (act) {
    const float4* wr = (const float4*)(w_hh + (size_t)(gt * 100 + j) * HH);
#pragma unroll
    for (int kk = 0; kk < 25; ++kk) {
      float4 a = wr[kk];
      whh[2 * kk]     = __builtin_amdgcn_cvt_pkrtz(a.x, a.y);
      whh[2 * kk + 1] = __builtin_amdgcn_cvt_pkrtz(a.z, a.w);
    }
  }
  if (tid < 52) { hls[0][tid] = 0u; hls[1][tid] = 0u; }

  // per-lane activation constants: sigmoid for i,f,o; tanh for g (gt==2)
  const float kk2 = (gt == 2) ? (2.f * F_LOG2E) : (-F_LOG2E);
  const float cA  = (gt == 2) ? -2.f : 1.f;
  const float cB  = (gt == 2) ? 1.f : 0.f;

  const unsigned short* gb = gin16 + ((size_t)(b * 2 + dir) * TT) * NG + tid;
  unsigned short* hcb = hc16 + (size_t)b * TT * 200 + dir * 100 + j;

  float c = 0.f;
  unsigned short g0 = 0, g1 = 0;
  if (act) {
    g0 = gb[(size_t)(dir ? 511 : 0) * NG];
    g1 = gb[(size_t)(dir ? 510 : 1) * NG];
  }
  __syncthreads();

  for (int t = 0; t < TT; ++t) {
    if (act) {
      int tn  = (t + 2 < TT) ? (t + 2) : (TT - 1);
      int ttn = dir ? (TT - 1 - tn) : tn;
      unsigned short g2 = gb[(size_t)ttn * NG];

      const unsigned int* hp = hls[t & 1];
      float a0 = (float)__builtin_bit_cast(__fp16, g0);
      float a1 = 0.f, a2 = 0.f, a3 = 0.f;
#pragma unroll
      for (int g = 0; g < 12; ++g) {
        uint4 u = ((const uint4*)hp)[g];
        a0 = fdot2(whh[4 * g],     bc_h2(u.x), a0);
        a1 = fdot2(whh[4 * g + 1], bc_h2(u.y), a1);
        a2 = fdot2(whh[4 * g + 2], bc_h2(u.z), a2);
        a3 = fdot2(whh[4 * g + 3], bc_h2(u.w), a3);
      }
      a0 = fdot2(whh[48], bc_h2(hp[48]), a0);
      a1 = fdot2(whh[49], bc_h2(hp[49]), a1);
      float gate = (a0 + a1) + (a2 + a3);

      float y  = fexp2(kk2 * gate);
      float rr = frcp(1.f + y);
      float actv = fmaf(cA, rr, cB);

      float iv = __shfl(actv, bl4);
      float fv = __shfl(actv, bl4 + 1);
      float gv = __shfl(actv, bl4 + 2);
      float ov = __shfl(actv, bl4 + 3);
      c = fmaf(fv, c, iv * gv);
      float hv = ov * tanh_f(c);

      if (gt == 0) {
        int tt = dir ? (TT - 1 - t) : t;
        __fp16 h16 = (__fp16)hv;
        ((__fp16*)(hls[(t + 1) & 1]))[j] = h16;
        hcb[(size_t)tt * 200] = __builtin_bit_cast(unsigned short, h16);
      }
      g0 = g1; g1 = g2;
    }
    lds_barrier();
  }
}

// ---------------------------------------------------------------------------
// FALLBACK scan (small ws): computes x-side in-loop, writes hc16 f16.
// ---------------------------------------------------------------------------
__global__ __launch_bounds__(512, 2) void lstm_scan_fb(
    const int* __restrict__ tok, const float* __restrict__ emb,
    const float* __restrict__ w_ih_f, const float* __restrict__ w_hh_f,
    const float* __restrict__ b_ih_f, const float* __restrict__ b_hh_f,
    const float* __restrict__ w_ih_b, const float* __restrict__ w_hh_b,
    const float* __restrict__ b_ih_b, const float* __restrict__ b_hh_b,
    unsigned short* __restrict__ hc16)
{
  const int tid = threadIdx.x;
  const int b   = blockIdx.x & 127;
  const int dir = blockIdx.x >> 7;

  const float* w_ih = dir ? w_ih_b : w_ih_f;
  const float* w_hh = dir ? w_hh_b : w_hh_f;
  const float* b_ih = dir ? b_ih_b : b_ih_f;
  const float* b_hh = dir ? b_hh_b : b_hh_f;

  __shared__ __align__(16) unsigned int xs[2][64];
  __shared__ __align__(16) unsigned int hls[64];
  __shared__ float gl[NG];

  h2_t wih[50], whh[50];
  float bias = 0.f;
  if (tid < NG) {
    const float4* wi = (const float4*)(w_ih + tid * DD);
    const float4* wh = (const float4*)(w_hh + tid * DD);
#pragma unroll
    for (int kk = 0; kk < 25; ++kk) {
      float4 a = wi[kk];
      wih[2 * kk]     = __builtin_amdgcn_cvt_pkrtz(a.x, a.y);
      wih[2 * kk + 1] = __builtin_amdgcn_cvt_pkrtz(a.z, a.w);
      float4 c = wh[kk];
      whh[2 * kk]     = __builtin_amdgcn_cvt_pkrtz(c.x, c.y);
      whh[2 * kk + 1] = __builtin_amdgcn_cvt_pkrtz(c.z, c.w);
    }
    bias = b_ih[tid] + b_hh[tid];
  }
  if (tid < 2) { xs[0][50 + tid] = 0u; xs[1][50 + tid] = 0u; hls[50 + tid] = 0u; }
  if (tid < 50) hls[tid] = 0u;

  const int base = b * TT;
  if (tid >= 448 && tid < 498) {
    int tt0 = dir ? (TT - 1) : 0;
    int i = tid - 448;
    int tk = tok[base + tt0];
    float2 v = ((const float2*)(emb + (size_t)tk * DD))[i];
    xs[0][i] = pk(v.x, v.y);
  }
  __syncthreads();

  float cst = 0.f;
  unsigned short* hcb = hc16 + (size_t)base * 200 + dir * 100;

  for (int t = 0; t < TT; ++t) {
    const int buf = t & 1;
    const int tt  = dir ? (TT - 1 - t) : t;

    if (tid < NG) {
      float a0 = bias, a1 = 0.f, a2 = 0.f, a3 = 0.f;
      const unsigned int* xp = xs[buf];
#pragma unroll
      for (int g = 0; g < 13; ++g) {
        uint4 u = ((const uint4*)xp)[g];
        const int k = 4 * g;
        a0 = fdot2(wih[k], bc_h2(u.x), a0);
        a1 = fdot2(wih[k + 1], bc_h2(u.y), a1);
        if (k + 2 < 50) a2 = fdot2(wih[k + 2], bc_h2(u.z), a2);
        if (k + 3 < 50) a3 = fdot2(wih[k + 3], bc_h2(u.w), a3);
      }
#pragma unroll
      for (int g = 0; g < 13; ++g) {
        uint4 u = ((const uint4*)hls)[g];
        const int k = 4 * g;
        a0 = fdot2(whh[k], bc_h2(u.x), a0);
        a1 = fdot2(whh[k + 1], bc_h2(u.y), a1);
        if (k + 2 < 50) a2 = fdot2(whh[k + 2], bc_h2(u.z), a2);
        if (k + 3 < 50) a3 = fdot2(whh[k + 3], bc_h2(u.w), a3);
      }
      float accs = (a0 + a1) + (a2 + a3);
      float av = (tid >= 200 && tid < 300) ? tanh_f(accs) : sigmoid_f(accs);
      gl[tid] = av;
    } else if (tid >= 448 && tid < 498 && t < TT - 1) {
      int ttn = dir ? (TT - 2 - t) : (t + 1);
      int i = tid - 448;
      int tk = tok[base + ttn];
      float2 v = ((const float2*)(emb + (size_t)tk * DD))[i];
      xs[buf ^ 1][i] = pk(v.x, v.y);
    }
    __syncthreads();

    if (tid < HH) {
      float gi = gl[tid], gf = gl[tid + 100], gg = gl[tid + 200], go = gl[tid + 300];
      cst = gf * cst + gi * gg;
      float hv = go * tanh_f(cst);
      __fp16 h16 = (__fp16)hv;
      ((__fp16*)hls)[tid] = h16;
      hcb[(size_t)tt * 200 + tid] = __builtin_bit_cast(unsigned short, h16);
    }
    __syncthreads();
  }
}

// ---------------------------------------------------------------------------
// Emissions (f16 in): em[m,l] = b_tag[l] + sum_k hc16[m,k]*w_tag[l,k].
// h tile + packed w_tag staged in LDS; fdot2 inner loop.
// ---------------------------------------------------------------------------
__global__ __launch_bounds__(256, 2) void emis2(
    const unsigned short* __restrict__ hc16, const float* __restrict__ w_tag,
    const float* __restrict__ b_tag, float* __restrict__ em)
{
  __shared__ unsigned int hsh[64 * 101];
  __shared__ unsigned int wsh[25 * 100];
  const int tid = threadIdx.x;
  const size_t m0 = (size_t)blockIdx.x * 64;

  const unsigned int* hcu = (const unsigned int*)hc16;
  for (int i = tid; i < 64 * 100; i += 256) {
    int r = i / 100;
    int k = i - r * 100;
    hsh[r * 101 + k] = hcu[m0 * 100 + i];
  }
  for (int i = tid; i < 25 * 100; i += 256) {
    float2 wv = ((const float2*)w_tag)[i];
    wsh[i] = pk(wv.x, wv.y);
  }
  __syncthreads();

  const int r = tid & 63, q = tid >> 6;
  int lidx[7];
  bool lv[7];
  float acc[7];
#pragma unroll
  for (int ii = 0; ii < 7; ++ii) {
    int l = q + 4 * ii;
    lv[ii] = (l < LL);
    lidx[ii] = lv[ii] ? l : 0;
    acc[ii] = lv[ii] ? b_tag[lidx[ii]] : 0.f;
  }
  const unsigned int* hrow = hsh + r * 101;
#pragma unroll 2
  for (int k = 0; k < 100; ++k) {
    h2_t hv = bc_h2(hrow[k]);
#pragma unroll
    for (int ii = 0; ii < 7; ++ii)
      acc[ii] = fdot2(hv, bc_h2(wsh[lidx[ii] * 100 + k]), acc[ii]);
  }
#pragma unroll
  for (int ii = 0; ii < 7; ++ii)
    if (lv[ii]) em[(m0 + r) * LL + lidx[ii]] = acc[ii];
}

// ---------------------------------------------------------------------------
// CRF gold path score
// ---------------------------------------------------------------------------
__global__ __launch_bounds__(512, 2) void crf_gold(
    const int* __restrict__ tags, const int* __restrict__ lengths,
    const float* __restrict__ em, const float* __restrict__ trans,
    const float* __restrict__ startt, const float* __restrict__ endt,
    float* __restrict__ gold)
{
  const int b = blockIdx.x, t = threadIdx.x;
  const int len = lengths[b];
  float term = 0.f;
  if (t < len) {
    int tg = tags[b * TT + t];
    float e = em[((size_t)b * TT + t) * LL + tg];
    if (t == 0) term = startt[tg] + e;
    else        term = trans[tags[b * TT + t - 1] * LL + tg] + e;
    if (t == len - 1) term += endt[tg];
  }
  __shared__ float red[8];
  for (int o = 32; o > 0; o >>= 1) term += __shfl_down(term, o);
  if ((t & 63) == 0) red[t >> 6] = term;
  __syncthreads();
  if (t == 0) {
    float s = 0.f;
#pragma unroll
    for (int w = 0; w < 8; ++w) s += red[w];
    gold[b] = s;
  }
}

// ---------------------------------------------------------------------------
// CRF partition: split fwd/bwd scan, half-wave lse split, em prefetch.
// ---------------------------------------------------------------------------
__global__ __launch_bounds__(64) void crf_scan2(
    const float* __restrict__ em, const float* __restrict__ trans,
    const float* __restrict__ startt, const float* __restrict__ endt,
    float* __restrict__ ab)
{
  const int lane = threadIdx.x;
  const int b    = blockIdx.x >> 1;
  const int side = blockIdx.x & 1;
  const int half = lane >> 5;
  const int jl   = lane & 31;
  const int j    = (jl < LL) ? jl : 0;
  const float* emb_ = em + (size_t)b * TT * LL;
  const int ibase = half ? 13 : 0;
  const int icnt  = half ? 12 : 13;

  float tc[13];
#pragma unroll
  for (int k = 0; k < 13; ++k) {
    int i = ibase + k;
    float tv = 0.f;
    if (k < icnt) tv = (side == 0) ? trans[i * LL + j] : trans[j * LL + i];
    tc[k] = (k < icnt) ? tv * F_LOG2E : -100000.f;
  }

  float a, C = 0.f;
  if (side == 0) {
    a = (startt[j] + emb_[j]) * F_LOG2E;
    float emn = emb_[LL + j];
    for (int t = 1; t < 256; ++t) {
      float emc = emn;
      int tn = (t + 1 < 256) ? t + 1 : t;
      emn = emb_[(size_t)tn * LL + j];
      float s = rl(a, 0); a -= s; C += s;
      float p0 = 0.f, p1 = 0.f;
#pragma unroll
      for (int k = 0; k < 13; ++k) {
        float ai = __shfl(a, ibase + k);
        float e = fexp2(ai + tc[k]);
        if (k & 1) p1 += e; else p0 += e;
      }
      float p = p0 + p1;
      p += __shfl_xor(p, 32);
      a = flog2(p) + emc * F_LOG2E;
    }
  } else {
    a = endt[j] * F_LOG2E;
    float emn = emb_[(size_t)(TT - 1) * LL + j];
    for (int stp = 0; stp < 256; ++stp) {
      int t1 = TT - 1 - stp;
      float emc = emn;
      int t1n = (stp + 1 < 256) ? (t1 - 1) : t1;
      emn = emb_[(size_t)t1n * LL + j];
      float v = a + emc * F_LOG2E;
      float s = rl(v, 0); v -= s; C += s;
      float p0 = 0.f, p1 = 0.f;
#pragma unroll
      for (int k = 0; k < 13; ++k) {
        float vi = __shfl(v, ibase + k);
        float e = fexp2(vi + tc[k]);
        if (k & 1) p1 += e; else p0 += e;
      }
      float p = p0 + p1;
      p += __shfl_xor(p, 32);
      a = flog2(p);
    }
  }
  if (lane < LL)
    ab[((size_t)b * 2 + side) * LL + lane] = (a + C) * F_LN2;
}

// ---------------------------------------------------------------------------
// Final reduce
// ---------------------------------------------------------------------------
__global__ __launch_bounds__(128, 4) void crf_final(
    const float* __restrict__ ab, const float* __restrict__ gold,
    float* __restrict__ out)
{
  const int b = threadIdx.x;
  float v[LL];
  float m = -1e30f;
#pragma unroll
  for (int l = 0; l < LL; ++l) {
    v[l] = ab[((size_t)b * 2) * LL + l] + ab[((size_t)b * 2 + 1) * LL + l];
    m = fmaxf(m, v[l]);
  }
  float s = 0.f;
#pragma unroll
  for (int l = 0; l < LL; ++l) s += fexp2((v[l] - m) * F_LOG2E);
  float nll = (m + flog2(s) * F_LN2) - gold[b];

  for (int o = 32; o > 0; o >>= 1) nll += __shfl_down(nll, o);
  __shared__ float r2[2];
  if ((b & 63) == 0) r2[b >> 6] = nll;
  __syncthreads();
  if (b == 0) out[0] = r2[0] + r2[1];
}

extern "C" void kernel_launch(void* const* d_in, const int* in_sizes, int n_in,
                              void* d_out, int out_size, void* d_ws, size_t ws_size,
                              hipStream_t stream) {
  const int*   tok   = (const int*)d_in[0];
  const int*   tags  = (const int*)d_in[1];
  const int*   lens  = (const int*)d_in[2];
  const float* emb   = (const float*)d_in[3];
  const float* wif   = (const float*)d_in[4];
  const float* whf   = (const float*)d_in[5];
  const float* bif   = (const float*)d_in[6];
  const float* bhf   = (const float*)d_in[7];
  const float* wib   = (const float*)d_in[8];
  const float* whb   = (const float*)d_in[9];
  const float* bib   = (const float*)d_in[10];
  const float* bhb   = (const float*)d_in[11];
  const float* wtag  = (const float*)d_in[12];
  const float* btag  = (const float*)d_in[13];
  const float* trans = (const float*)d_in[14];
  const float* st    = (const float*)d_in[15];
  const float* en    = (const float*)d_in[16];

  char* wsb = (char*)d_ws;
  unsigned short* hc16 = (unsigned short*)wsb;                 // 26,214,400 B
  float* em   = (float*)(wsb + 26214400);                      //  6,553,600 B
  float* gold = (float*)(wsb + 32768000);                      //        512 B
  float* ab   = (float*)(wsb + 32768512);                      //     25,600 B
  unsigned short* gin16 = (unsigned short*)(wsb + 32794112);   // 104,857,600 B
  const size_t need = 137651712ULL;

  if (ws_size >= need) {
    gin_gemm2<<<1024, 448, 0, stream>>>(tok, emb, wif, bif, bhf, wib, bib, bhb, gin16);
    lstm_scan3<<<256, 448, 0, stream>>>(gin16, whf, whb, hc16);
  } else {
    lstm_scan_fb<<<256, 512, 0, stream>>>(tok, emb, wif, whf, bif, bhf,
                                          wib, whb, bib, bhb, hc16);
  }
  emis2<<<1024, 256, 0, stream>>>(hc16, wtag, btag, em);
  crf_gold<<<128, 512, 0, stream>>>(tags, lens, em, trans, st, en, gold);
  crf_scan2<<<256, 64, 0, stream>>>(em, trans, st, en, ab);
  crf_final<<<1, 128, 0, stream>>>(ab, gold, (float*)d_out);
}